// Round 2
// baseline (301.495 us; speedup 1.0000x reference)
//
#include <hip/hip_runtime.h>

// DNA transport NEGF: per (b,e) invert A = (E*I - H) + i*diag(0.5*(gL+gR)),
// DOS = -Im tr(Gr), T = sum_ij gL_i gR_j |Gr_ij|^2, plus H scatter output.
//
// Lane j of a 20-lane subgroup owns column j of A (in-place Gauss-Jordan ->
// same registers end as column j of Gr). 3 subgroups/wave, 4 waves/block,
// grid = 1024 batches x 9 energy-chunks (12 energies each, 108 slots >= 100).
//
// Column-k broadcast via ds_bpermute straight from lane k's registers:
// no LDS stage, no write->read round trip, no barriers in the k-loop.
//
// No pivoting: imag(x^* A x) > 0 for all leading blocks => pivots bounded
// below by min_i 0.5(gL_i+gR_i). Stable in fp32 (R0: absmax 3.9e-3).

#define H_N   20
#define NE    100
#define T_OFF 0
#define D_OFF 102400
#define H_OFF 204800

__device__ __forceinline__ int triIdx(int i, int j) {  // i <= j, row-major triu
    return i * H_N - ((i * (i - 1)) >> 1) + (j - i);
}

__device__ __forceinline__ float bperm(int addr, float v) {
    return __int_as_float(__builtin_amdgcn_ds_bpermute(addr, __float_as_int(v)));
}

__global__ __launch_bounds__(256, 6)
void negf_all(const float* __restrict__ tri,
              const float* __restrict__ GL,
              const float* __restrict__ GR,
              float* __restrict__ out)
{
    __shared__ float Hcm[400];          // column-major: Hcm[c*20 + r] = H[r][c]
    __shared__ float sgL[H_N], sgR[H_N], sgam[H_N];

    const int blk   = blockIdx.x;
    const int b     = blk / 9;
    const int chunk = blk - b * 9;
    const int tid   = threadIdx.x;

    // ---- stage H (column-major) + gammas into LDS ----
    const float* triB = tri + b * 210;
    #pragma unroll
    for (int u0 = 0; u0 < 2; ++u0) {
        int u = tid + u0 * 256;
        if (u < 400) {
            int c = u / 20, r = u - c * 20;
            int lo = r < c ? r : c;
            int hi = r < c ? c : r;
            Hcm[u] = triB[triIdx(lo, hi)];
        }
    }
    if (tid < H_N) {
        float l = GL[b * H_N + tid];
        float r = GR[b * H_N + tid];
        sgL[tid] = l; sgR[tid] = r; sgam[tid] = 0.5f * (l + r);
    }
    __syncthreads();

    // ---- H output (row-major), exact copy of inputs; one block per b ----
    if (chunk == 0) {
        #pragma unroll
        for (int u0 = 0; u0 < 2; ++u0) {
            int u = tid + u0 * 256;
            if (u < 400) {
                int r = u / 20, c = u - r * 20;
                out[H_OFF + b * 400 + u] = Hcm[c * 20 + r];
            }
        }
    }

    const int lane = tid & 63;
    const int wid  = tid >> 6;
    const int sw   = lane / 20;              // 0..2 active, 3 idle
    const int ll   = lane - sw * 20;         // 0..19 row/col id within subgroup
    const int sg   = wid * 3 + (sw < 3 ? sw : 0);
    const int e    = chunk * 12 + sg;
    if (sw == 3 || e >= NE) return;          // no barriers after this point

    const float gj   = sgR[ll];              // gammaR_j for this lane's column
    const float gamj = sgam[ll];
    const float E    = fmaf((float)e, 6.0f / 99.0f, -3.0f);

    // build column ll of A
    float2 col[H_N];
    #pragma unroll
    for (int i = 0; i < H_N; ++i) {
        float hv = Hcm[ll * 20 + i];
        col[i].x = (i == ll) ? (E - hv) : (-hv);
        col[i].y = (i == ll) ? gamj : 0.0f;
    }

    const int abase = (sw * 20) << 2;        // byte addr of subgroup base lane

    // ---- in-place Gauss-Jordan, fully unrolled, register broadcast ----
    #pragma unroll
    for (int k = 0; k < H_N; ++k) {
        const int addr = abase + (k << 2);
        // pivot first: start the reciprocal chain after one DS latency
        const float ykx = bperm(addr, col[k].x);
        const float yky = bperm(addr, col[k].y);
        const float den = fmaf(ykx, ykx, yky * yky);
        const float inv = __builtin_amdgcn_rcpf(den);
        const float px  =  ykx * inv;
        const float py  = -yky * inv;

        // t = col[k] * p ; lane k uses t = 1 + p (e_k substitution folded in)
        float tx = col[k].x * px - col[k].y * py;
        float ty = col[k].x * py + col[k].y * px;
        const bool isk  = (ll == k);
        const float tux = isk ? (1.0f + px) : tx;
        const float tuy = isk ? py          : ty;
        const float fkx = isk ? px : tx;     // final col[k]
        const float fky = isk ? py : ty;

        #pragma unroll
        for (int i = 0; i < H_N; ++i) {
            if (i == k) continue;
            const float yix = bperm(addr, col[i].x);   // reads pre-update col[i]
            const float yiy = bperm(addr, col[i].y);
            col[i].x = fmaf(-yix, tux, fmaf( yiy, tuy, col[i].x));
            col[i].y = fmaf(-yix, tuy, fmaf(-yiy, tux, col[i].y));
        }
        col[k].x = fkx;
        col[k].y = fky;
    }

    // ---- epilogue: T partial + diag Im, subgroup reduce, store ----
    float tv = 0.0f, dv = 0.0f;
    #pragma unroll
    for (int i = 0; i < H_N; ++i) {
        float aa = fmaf(col[i].x, col[i].x, col[i].y * col[i].y);
        tv = fmaf(sgL[i], aa, tv);
        dv = (i == ll) ? col[i].y : dv;
    }
    tv *= gj;

    #pragma unroll
    for (int d = 16; d >= 1; d >>= 1) {
        float t2 = __shfl(tv, lane + d, 64);
        float d2 = __shfl(dv, lane + d, 64);
        if (ll + d < 20) { tv += t2; dv += d2; }
    }
    if (ll == 0) {
        out[T_OFF + b * NE + e] = __log10f(fmaxf(tv, 1e-16f));
        out[D_OFF + b * NE + e] = __log10f(fmaxf(-dv, 1e-16f));
    }
}

extern "C" void kernel_launch(void* const* d_in, const int* in_sizes, int n_in,
                              void* d_out, int out_size, void* d_ws, size_t ws_size,
                              hipStream_t stream) {
    const float* tri = (const float*)d_in[0];
    const float* gL  = (const float*)d_in[1];
    const float* gR  = (const float*)d_in[2];
    float* out = (float*)d_out;
    negf_all<<<1024 * 9, 256, 0, stream>>>(tri, gL, gR, out);
}

// Round 3
// 223.673 us; speedup vs baseline: 1.3479x; 1.3479x over previous
//
#include <hip/hip_runtime.h>

// DNA transport NEGF: per (b,e) invert A = (E*I - H) + i*diag(0.5*(gL+gR)),
// DOS = -Im tr(Gr), T = sum_ij gL_i gR_j |Gr_ij|^2, plus H scatter output.
//
// Lane j of a 20-lane subgroup owns column j of A (in-place Gauss-Jordan ->
// same registers end as column j of Gr). 3 subgroups/wave, 4 waves/block.
// Grid = 1024 batches x 9 chunks (12 energies each; flat, no serial loop).
//
// Column-k broadcast: lane k stages its column to LDS as 10 x float4, all
// lanes read it back (same-address b128 reads broadcast conflict-free).
// R1 lesson: ds_bpermute variant (40 DS ops/step) + tight launch_bounds
// spilled col[] to scratch (VGPR=32) and regressed. Keep col in registers:
// launch_bounds(256,4) = 128-VGPR cap >> ~80 needed.
//
// No pivoting: imag(x^* A x) > 0 for all leading blocks => pivots bounded
// below by min_i 0.5(gL_i+gR_i). Stable in fp32 (R0/R1: absmax 3.9e-3).

#define H_N   20
#define NE    100
#define T_OFF 0
#define D_OFF 102400
#define H_OFF 204800

__device__ __forceinline__ int triIdx(int i, int j) {  // i <= j, row-major triu
    return i * H_N - ((i * (i - 1)) >> 1) + (j - i);
}

__global__ __launch_bounds__(256, 4)
void negf_all(const float* __restrict__ tri,
              const float* __restrict__ GL,
              const float* __restrict__ GR,
              float* __restrict__ out)
{
    __shared__ float Hcm[400];          // column-major: Hcm[c*20 + r] = H[r][c]
    __shared__ float sgL[H_N], sgR[H_N], sgam[H_N];
    __shared__ float4 stage[12][10];    // per-subgroup column broadcast

    const int blk   = blockIdx.x;
    const int b     = blk / 9;
    const int chunk = blk - b * 9;
    const int tid   = threadIdx.x;

    // ---- stage H (column-major) + gammas into LDS ----
    const float* triB = tri + b * 210;
    #pragma unroll
    for (int u0 = 0; u0 < 2; ++u0) {
        int u = tid + u0 * 256;
        if (u < 400) {
            int c = u / 20, r = u - c * 20;
            int lo = r < c ? r : c;
            int hi = r < c ? c : r;
            Hcm[u] = triB[triIdx(lo, hi)];
        }
    }
    if (tid < H_N) {
        float l = GL[b * H_N + tid];
        float r = GR[b * H_N + tid];
        sgL[tid] = l; sgR[tid] = r; sgam[tid] = 0.5f * (l + r);
    }
    __syncthreads();

    // ---- H output (row-major), exact copy of inputs; one block per b ----
    if (chunk == 0) {
        #pragma unroll
        for (int u0 = 0; u0 < 2; ++u0) {
            int u = tid + u0 * 256;
            if (u < 400) {
                int r = u / 20, c = u - r * 20;
                out[H_OFF + b * 400 + u] = Hcm[c * 20 + r];
            }
        }
    }

    const int lane = tid & 63;
    const int wid  = tid >> 6;
    const int sw   = lane / 20;              // 0..2 active, 3 idle
    const int ll   = lane - sw * 20;         // 0..19 row/col id within subgroup
    const int sg   = wid * 3 + (sw < 3 ? sw : 0);
    const int e    = chunk * 12 + sg;
    if (sw == 3 || e >= NE) return;          // no __syncthreads after this point

    const float gj   = sgR[ll];              // gammaR_j for this lane's column
    const float gamj = sgam[ll];
    const float E    = fmaf((float)e, 6.0f / 99.0f, -3.0f);

    // build column ll of A
    float2 col[H_N];
    #pragma unroll
    for (int i = 0; i < H_N; ++i) {
        float hv = Hcm[ll * 20 + i];
        col[i].x = (i == ll) ? (E - hv) : (-hv);
        col[i].y = (i == ll) ? gamj : 0.0f;
    }

    // ---- in-place Gauss-Jordan, fully unrolled (static reg indices) ----
    #pragma unroll
    for (int k = 0; k < H_N; ++k) {
        // lane k publishes its (pre-update) column
        if (ll == k) {
            #pragma unroll
            for (int q = 0; q < 10; ++q)
                stage[sg][q] = make_float4(col[2*q].x,   col[2*q].y,
                                           col[2*q+1].x, col[2*q+1].y);
        }
        __builtin_amdgcn_wave_barrier();
        float2 y[H_N];
        #pragma unroll
        for (int q = 0; q < 10; ++q) {
            float4 v = stage[sg][q];
            y[2*q].x   = v.x; y[2*q].y   = v.y;
            y[2*q+1].x = v.z; y[2*q+1].y = v.w;
        }
        __builtin_amdgcn_wave_barrier();

        // p = 1 / pivot (complex reciprocal)
        const float den = fmaf(y[k].x, y[k].x, y[k].y * y[k].y);
        const float inv = __builtin_amdgcn_rcpf(den);
        const float px  =  y[k].x * inv;
        const float py  = -y[k].y * inv;

        // t = col[k] * p ; lane k uses t = 1 + p (e_k substitution folded in)
        float tx = col[k].x * px - col[k].y * py;
        float ty = col[k].x * py + col[k].y * px;
        const bool isk  = (ll == k);
        const float tux = isk ? (1.0f + px) : tx;
        const float tuy = isk ? py          : ty;
        const float fkx = isk ? px : tx;    // final col[k]
        const float fky = isk ? py : ty;

        #pragma unroll
        for (int i = 0; i < H_N; ++i) {
            if (i == k) continue;
            col[i].x = fmaf(-y[i].x, tux, fmaf( y[i].y, tuy, col[i].x));
            col[i].y = fmaf(-y[i].x, tuy, fmaf(-y[i].y, tux, col[i].y));
        }
        col[k].x = fkx;
        col[k].y = fky;
    }

    // ---- epilogue: T partial + diag Im, subgroup reduce, store ----
    float tv = 0.0f, dv = 0.0f;
    #pragma unroll
    for (int i = 0; i < H_N; ++i) {
        float aa = fmaf(col[i].x, col[i].x, col[i].y * col[i].y);
        tv = fmaf(sgL[i], aa, tv);
        dv = (i == ll) ? col[i].y : dv;
    }
    tv *= gj;

    #pragma unroll
    for (int d = 16; d >= 1; d >>= 1) {
        float t2 = __shfl(tv, lane + d, 64);
        float d2 = __shfl(dv, lane + d, 64);
        if (ll + d < 20) { tv += t2; dv += d2; }
    }
    if (ll == 0) {
        out[T_OFF + b * NE + e] = __log10f(fmaxf(tv, 1e-16f));
        out[D_OFF + b * NE + e] = __log10f(fmaxf(-dv, 1e-16f));
    }
}

extern "C" void kernel_launch(void* const* d_in, const int* in_sizes, int n_in,
                              void* d_out, int out_size, void* d_ws, size_t ws_size,
                              hipStream_t stream) {
    const float* tri = (const float*)d_in[0];
    const float* gL  = (const float*)d_in[1];
    const float* gR  = (const float*)d_in[2];
    float* out = (float*)d_out;
    negf_all<<<1024 * 9, 256, 0, stream>>>(tri, gL, gR, out);
}

// Round 4
// 111.657 us; speedup vs baseline: 2.7002x; 2.0032x over previous
//
#include <hip/hip_runtime.h>

// DNA transport NEGF: per (b,e) invert A = (E*I - H) + i*diag(0.5*(gL+gR)),
// DOS = -Im tr(Gr), T = sum_ij gL_i gR_j |Gr_ij|^2, plus H scatter output.
//
// Lane j of a 20-lane subgroup owns column j of A (in-place Gauss-Jordan ->
// same registers end as column j of Gr). 3 subgroups/wave, 4 waves/block.
// Grid = 1024 batches x 9 chunks (12 energies each, flat).
//
// SYMMETRY BROADCAST: A is complex symmetric (no conjugation), and no-pivot
// in-place GJ preserves M[i][j] = sigma*M[j][i], sigma = -1 iff exactly one
// of i,j is processed. Pivot column y[i] = M[i][k] = +-M[k][i] = +-(element k
// of lane i's own column). So each step: ALL lanes ds_write_b64 their col[k]
// (1 instr) + 10 broadcast ds_read_b128 -- 11 DS ops/step vs 20 in R0 and
// ~60 in R2's rematerialized form. Signs fold into compile-time FMA signs.
//
// R1 lesson: ds_bpermute (40 DS/step) loses. R2 lesson: launch_bounds(256,4)
// makes the allocator remat y[] from LDS (VGPR 44, 40 scalar reads/step) ->
// DS-pipe-bound at 244us. Keep (256,2): col[] and quads stay in registers.
//
// No pivoting: imag(x^* A x) > 0 for all leading blocks => pivots bounded
// below by min_i 0.5(gL_i+gR_i). Stable in fp32 (R0-R2: absmax 3.9e-3).

#define H_N   20
#define NE    100
#define T_OFF 0
#define D_OFF 102400
#define H_OFF 204800

__device__ __forceinline__ int triIdx(int i, int j) {  // i <= j, row-major triu
    return i * H_N - ((i * (i - 1)) >> 1) + (j - i);
}

__global__ __launch_bounds__(256, 2)
void negf_all(const float* __restrict__ tri,
              const float* __restrict__ GL,
              const float* __restrict__ GR,
              float* __restrict__ out)
{
    __shared__ float Hcm[400];          // column-major: Hcm[c*20 + r] = H[r][c]
    __shared__ float sgL[H_N], sgR[H_N];
    __shared__ float4 stage[12][10];    // per-subgroup pivot-column broadcast

    const int blk   = blockIdx.x;
    const int b     = blk / 9;
    const int chunk = blk - b * 9;
    const int tid   = threadIdx.x;

    // ---- stage H (column-major) + gammas into LDS ----
    const float* triB = tri + b * 210;
    #pragma unroll
    for (int u0 = 0; u0 < 2; ++u0) {
        int u = tid + u0 * 256;
        if (u < 400) {
            int c = u / 20, r = u - c * 20;
            int lo = r < c ? r : c;
            int hi = r < c ? c : r;
            Hcm[u] = triB[triIdx(lo, hi)];
        }
    }
    if (tid < H_N) {
        sgL[tid] = GL[b * H_N + tid];
        sgR[tid] = GR[b * H_N + tid];
    }
    __syncthreads();

    // ---- H output (row-major), exact copy of inputs; one block per b ----
    if (chunk == 0) {
        #pragma unroll
        for (int u0 = 0; u0 < 2; ++u0) {
            int u = tid + u0 * 256;
            if (u < 400) {
                int r = u / 20, c = u - r * 20;
                out[H_OFF + b * 400 + u] = Hcm[c * 20 + r];
            }
        }
    }

    const int lane = tid & 63;
    const int wid  = tid >> 6;
    const int sw   = lane / 20;              // 0..2 active, 3 idle
    const int ll   = lane - sw * 20;         // 0..19 row/col id within subgroup
    const int sg   = wid * 3 + (sw < 3 ? sw : 0);
    const int e    = chunk * 12 + sg;
    if (sw == 3 || e >= NE) return;          // no __syncthreads after this point

    const float gj   = sgR[ll];              // gammaR_j for this lane's column
    const float gamj = 0.5f * (sgL[ll] + gj);
    const float E    = fmaf((float)e, 6.0f / 99.0f, -3.0f);

    // build column ll of A
    float2 col[H_N];
    #pragma unroll
    for (int i = 0; i < H_N; ++i) {
        float hv = Hcm[ll * 20 + i];
        col[i].x = (i == ll) ? (E - hv) : (-hv);
        col[i].y = (i == ll) ? gamj : 0.0f;
    }

    float2* const myStage = (float2*)&stage[sg][0];

    // ---- in-place Gauss-Jordan, fully unrolled (static reg indices) ----
    #pragma unroll
    for (int k = 0; k < H_N; ++k) {
        // every lane publishes its element k: stage[sg][i] = M[k][i]
        myStage[ll] = col[k];                // one ds_write_b64, whole wave
        __builtin_amdgcn_wave_barrier();
        float4 v[10];
        #pragma unroll
        for (int q = 0; q < 10; ++q) v[q] = stage[sg][q];
        __builtin_amdgcn_wave_barrier();

        // pivot = s_k = M[k][k]
        const float ykx = (k & 1) ? v[k >> 1].z : v[k >> 1].x;
        const float yky = (k & 1) ? v[k >> 1].w : v[k >> 1].y;
        const float den = fmaf(ykx, ykx, yky * yky);
        const float inv = __builtin_amdgcn_rcpf(den);
        const float px  =  ykx * inv;
        const float py  = -yky * inv;

        // t = col[k] * p ; lane k uses t = 1 + p (e_k substitution folded in)
        const float tx  = col[k].x * px - col[k].y * py;
        const float ty  = col[k].x * py + col[k].y * px;
        const bool  isk = (ll == k);
        const float tux = isk ? (1.0f + px) : tx;
        const float tuy = isk ? py          : ty;
        const float fkx = isk ? px : tx;     // final col[k]
        const float fky = isk ? py : ty;

        // col[i] -= y[i]*tu, with y[i] = sigma * s_i, sigma = -1 for i<k
        #pragma unroll
        for (int i = 0; i < H_N; ++i) {
            if (i == k) continue;
            const float sx = (i & 1) ? v[i >> 1].z : v[i >> 1].x;
            const float sy = (i & 1) ? v[i >> 1].w : v[i >> 1].y;
            if (i < k) {   // y = -s
                col[i].x = fmaf( sx, tux, fmaf(-sy, tuy, col[i].x));
                col[i].y = fmaf( sx, tuy, fmaf( sy, tux, col[i].y));
            } else {       // y = +s
                col[i].x = fmaf(-sx, tux, fmaf( sy, tuy, col[i].x));
                col[i].y = fmaf(-sx, tuy, fmaf(-sy, tux, col[i].y));
            }
        }
        col[k].x = fkx;
        col[k].y = fky;
    }

    // ---- epilogue: T partial + diag Im, subgroup reduce, store ----
    float tv = 0.0f, dv = 0.0f;
    #pragma unroll
    for (int i = 0; i < H_N; ++i) {
        float aa = fmaf(col[i].x, col[i].x, col[i].y * col[i].y);
        tv = fmaf(sgL[i], aa, tv);
        dv = (i == ll) ? col[i].y : dv;
    }
    tv *= gj;

    #pragma unroll
    for (int d = 16; d >= 1; d >>= 1) {
        float t2 = __shfl(tv, lane + d, 64);
        float d2 = __shfl(dv, lane + d, 64);
        if (ll + d < 20) { tv += t2; dv += d2; }
    }
    if (ll == 0) {
        out[T_OFF + b * NE + e] = __log10f(fmaxf(tv, 1e-16f));
        out[D_OFF + b * NE + e] = __log10f(fmaxf(-dv, 1e-16f));
    }
}

extern "C" void kernel_launch(void* const* d_in, const int* in_sizes, int n_in,
                              void* d_out, int out_size, void* d_ws, size_t ws_size,
                              hipStream_t stream) {
    const float* tri = (const float*)d_in[0];
    const float* gL  = (const float*)d_in[1];
    const float* gR  = (const float*)d_in[2];
    float* out = (float*)d_out;
    negf_all<<<1024 * 9, 256, 0, stream>>>(tri, gL, gR, out);
}

// Round 5
// 111.157 us; speedup vs baseline: 2.7123x; 1.0045x over previous
//
#include <hip/hip_runtime.h>

// DNA transport NEGF: per (b,e) invert A = (E*I - H) + i*diag(0.5*(gL+gR)),
// DOS = -Im tr(Gr), T = sum_ij gL_i gR_j |Gr_ij|^2, plus H scatter output.
//
// Lane j of a 20-lane subgroup owns column j of A (in-place Gauss-Jordan ->
// same registers end as column j of Gr). 3 subgroups/wave, 4 waves/block.
// Grid = 1024 batches x 9 chunks (12 energies each, flat).
//
// SYMMETRY BROADCAST (R3): no-pivot GJ on complex-symmetric A preserves
// M[i][j] = sigma*M[j][i] (sigma=-1 iff exactly one of i,j processed), so
// the pivot column is readable from each lane's own col[k]: one wave-wide
// ds_write_b64 + 10 broadcast ds_read_b128 per step. Signs fold into FMAs.
//
// PACKED FP32 (R4): the complex update col[i] -= y[i]*tu is written as
// <2 x float> fma so LLVM emits v_pk_fma_f32 (gfx90a+ packed FP32, per-half
// neg + op_sel fold the sign pattern and the [tu.y,tu.x] swap): 2 packed
// FMAs per row instead of 8 scalar -> the dominant VALU cost halves+.
// R3 counters: VALUBusy 92-95% -> VALU-issue-bound; this cuts issue count.
//
// R1 lesson: ds_bpermute (40 DS/step) loses. R2 lesson: launch_bounds(256,4)
// remats y[] from LDS -> DS-bound. Keep (256,2); col[] stays in registers.
//
// No pivoting: imag(x^* A x) > 0 for all leading blocks => pivots bounded
// below by min_i 0.5(gL_i+gR_i). Stable in fp32 (R0-R3: absmax 3.9e-3).

typedef float f32x2 __attribute__((ext_vector_type(2)));

#define H_N   20
#define NE    100
#define T_OFF 0
#define D_OFF 102400
#define H_OFF 204800

__device__ __forceinline__ int triIdx(int i, int j) {  // i <= j, row-major triu
    return i * H_N - ((i * (i - 1)) >> 1) + (j - i);
}

// col -= (+s) * tu  (complex mul, unconjugated; for unprocessed rows i > k)
__device__ __forceinline__ f32x2 upd_pos(f32x2 c, f32x2 s, f32x2 tu, f32x2 tus) {
    f32x2 a; a.x =  s.y; a.y = -s.y;         // [ sy, -sy]
    c = __builtin_elementwise_fma(a, tus, c); // c += [sy*tuy, -sy*tux]
    f32x2 b; b.x = -s.x; b.y = -s.x;         // [-sx, -sx]
    return __builtin_elementwise_fma(b, tu, c); // c += [-sx*tux, -sx*tuy]
}

// col -= (-s) * tu  (mirror sign; for processed rows i < k)
__device__ __forceinline__ f32x2 upd_neg(f32x2 c, f32x2 s, f32x2 tu, f32x2 tus) {
    f32x2 a; a.x = -s.y; a.y =  s.y;
    c = __builtin_elementwise_fma(a, tus, c);
    f32x2 b; b.x =  s.x; b.y =  s.x;
    return __builtin_elementwise_fma(b, tu, c);
}

__global__ __launch_bounds__(256, 2)
void negf_all(const float* __restrict__ tri,
              const float* __restrict__ GL,
              const float* __restrict__ GR,
              float* __restrict__ out)
{
    __shared__ float Hcm[400];          // column-major: Hcm[c*20 + r] = H[r][c]
    __shared__ float sgL[H_N], sgR[H_N];
    __shared__ float4 stage[12][10];    // per-subgroup pivot-column broadcast

    const int blk   = blockIdx.x;
    const int b     = blk / 9;
    const int chunk = blk - b * 9;
    const int tid   = threadIdx.x;

    // ---- stage H (column-major) + gammas into LDS ----
    const float* triB = tri + b * 210;
    #pragma unroll
    for (int u0 = 0; u0 < 2; ++u0) {
        int u = tid + u0 * 256;
        if (u < 400) {
            int c = u / 20, r = u - c * 20;
            int lo = r < c ? r : c;
            int hi = r < c ? c : r;
            Hcm[u] = triB[triIdx(lo, hi)];
        }
    }
    if (tid < H_N) {
        sgL[tid] = GL[b * H_N + tid];
        sgR[tid] = GR[b * H_N + tid];
    }
    __syncthreads();

    // ---- H output (row-major), exact copy of inputs; one block per b ----
    if (chunk == 0) {
        #pragma unroll
        for (int u0 = 0; u0 < 2; ++u0) {
            int u = tid + u0 * 256;
            if (u < 400) {
                int r = u / 20, c = u - r * 20;
                out[H_OFF + b * 400 + u] = Hcm[c * 20 + r];
            }
        }
    }

    const int lane = tid & 63;
    const int wid  = tid >> 6;
    const int sw   = lane / 20;              // 0..2 active, 3 idle
    const int ll   = lane - sw * 20;         // 0..19 row/col id within subgroup
    const int sg   = wid * 3 + (sw < 3 ? sw : 0);
    const int e    = chunk * 12 + sg;
    if (sw == 3 || e >= NE) return;          // no __syncthreads after this point

    const float gj   = sgR[ll];              // gammaR_j for this lane's column
    const float gamj = 0.5f * (sgL[ll] + gj);
    const float E    = fmaf((float)e, 6.0f / 99.0f, -3.0f);

    // build column ll of A
    f32x2 col[H_N];
    #pragma unroll
    for (int i = 0; i < H_N; ++i) {
        float hv = Hcm[ll * 20 + i];
        col[i].x = (i == ll) ? (E - hv) : (-hv);
        col[i].y = (i == ll) ? gamj : 0.0f;
    }

    f32x2* const myStage = (f32x2*)&stage[sg][0];

    // ---- in-place Gauss-Jordan, fully unrolled (static reg indices) ----
    #pragma unroll
    for (int k = 0; k < H_N; ++k) {
        // every lane publishes its element k: stage[sg][i] = M[k][i]
        myStage[ll] = col[k];                // one ds_write_b64, whole wave
        __builtin_amdgcn_wave_barrier();
        f32x2 y[H_N];
        #pragma unroll
        for (int q = 0; q < 10; ++q) {
            float4 v = stage[sg][q];
            y[2*q].x   = v.x; y[2*q].y   = v.y;
            y[2*q+1].x = v.z; y[2*q+1].y = v.w;
        }
        __builtin_amdgcn_wave_barrier();

        // pivot = s_k = M[k][k]; p = 1/pivot (complex reciprocal)
        const float den = fmaf(y[k].x, y[k].x, y[k].y * y[k].y);
        const float inv = __builtin_amdgcn_rcpf(den);
        const float px  =  y[k].x * inv;
        const float py  = -y[k].y * inv;

        // t = col[k] * p (packed); lane k uses tu = [1+px, py]
        f32x2 pr;   pr.x  = px;        pr.y  = py;
        f32x2 prs;  prs.x = py;        prs.y = px;
        f32x2 ckx;  ckx.x = col[k].x;  ckx.y = col[k].x;
        f32x2 cky;  cky.x = -col[k].y; cky.y = col[k].y;
        f32x2 t = __builtin_elementwise_fma(ckx, pr, cky * prs);

        const bool isk = (ll == k);
        f32x2 onep; onep.x = 1.0f + px; onep.y = py;
        f32x2 tu = isk ? onep : t;           // 2 cndmask
        f32x2 fk = isk ? pr   : t;           // final col[k], 2 cndmask
        f32x2 tus; tus.x = tu.y; tus.y = tu.x;

        // col[i] -= y[i]*tu, with y[i] = sigma * s_i, sigma = -1 for i<k
        #pragma unroll
        for (int i = 0; i < H_N; ++i) {
            if (i == k) continue;
            col[i] = (i < k) ? upd_neg(col[i], y[i], tu, tus)
                             : upd_pos(col[i], y[i], tu, tus);
        }
        col[k] = fk;
    }

    // ---- epilogue: T partial + diag Im, subgroup reduce, store ----
    float tv = 0.0f, dv = 0.0f;
    #pragma unroll
    for (int i = 0; i < H_N; ++i) {
        float aa = fmaf(col[i].x, col[i].x, col[i].y * col[i].y);
        tv = fmaf(sgL[i], aa, tv);
        dv = (i == ll) ? col[i].y : dv;
    }
    tv *= gj;

    #pragma unroll
    for (int d = 16; d >= 1; d >>= 1) {
        float t2 = __shfl(tv, lane + d, 64);
        float d2 = __shfl(dv, lane + d, 64);
        if (ll + d < 20) { tv += t2; dv += d2; }
    }
    if (ll == 0) {
        out[T_OFF + b * NE + e] = __log10f(fmaxf(tv, 1e-16f));
        out[D_OFF + b * NE + e] = __log10f(fmaxf(-dv, 1e-16f));
    }
}

extern "C" void kernel_launch(void* const* d_in, const int* in_sizes, int n_in,
                              void* d_out, int out_size, void* d_ws, size_t ws_size,
                              hipStream_t stream) {
    const float* tri = (const float*)d_in[0];
    const float* gL  = (const float*)d_in[1];
    const float* gR  = (const float*)d_in[2];
    float* out = (float*)d_out;
    negf_all<<<1024 * 9, 256, 0, stream>>>(tri, gL, gR, out);
}

// Round 6
// 102.293 us; speedup vs baseline: 2.9474x; 1.0867x over previous
//
#include <hip/hip_runtime.h>

// DNA transport NEGF: per (b,e) invert A = (E*I - H) + i*diag(0.5*(gL+gR)),
// DOS = -Im tr(Gr), T = sum_ij gL_i gR_j |Gr_ij|^2, plus H scatter output.
//
// Lane j of a 20-lane subgroup owns column j of A (in-place Gauss-Jordan ->
// same registers end as column j of Gr). 3 subgroups/wave, 4 waves/block.
// Grid = 1024 batches x 9 chunks (12 energies each, flat).
//
// SYMMETRY BROADCAST (R3): no-pivot GJ on complex-symmetric A preserves
// M[i][j] = sigma*M[j][i] (sigma=-1 iff exactly one of i,j processed), so
// the pivot column is readable from each lane's own col[k]: one wave-wide
// ds_write_b64 + 10 broadcast ds_read_b128 per step. Signs fold into FMAs.
//
// FORCED v_pk_fma_f32 (R5): R4's intrinsic form was NOT selected as packed
// math (counters: only ~12% VALU-issue drop; VGPR=36 -> col[] bounced
// through AGPRs via v_accvgpr moves). The complex update's sign pattern and
// the [tu.y,tu.x] swap map exactly onto VOP3P op_sel/op_sel_hi/neg_lo/neg_hi
// modifiers -> inline asm emits exactly 2 v_pk_fma_f32 per row, zero
// auxiliary constant-building, and pins operands to arch VGPRs.
//
// R1 lesson: ds_bpermute (40 DS/step) loses. R2 lesson: tight launch bounds
// remat y[] from LDS -> DS-bound. Keep (256,2).
//
// No pivoting: imag(x^* A x) > 0 for all leading blocks => pivots bounded
// below by min_i 0.5(gL_i+gR_i). Stable in fp32 (R0-R4: absmax 3.9e-3).

typedef float f32x2 __attribute__((ext_vector_type(2)));
typedef float f32x4 __attribute__((ext_vector_type(4)));

#define H_N   20
#define NE    100
#define T_OFF 0
#define D_OFF 102400
#define H_OFF 204800

__device__ __forceinline__ int triIdx(int i, int j) {  // i <= j, row-major triu
    return i * H_N - ((i * (i - 1)) >> 1) + (j - i);
}

// col -= (+s)*tu : lo: c.x += s.y*tu.y - s.x*tu.x ; hi: c.y += -s.y*tu.x - s.x*tu.y
__device__ __forceinline__ void upd_pos(f32x2& c, f32x2 s, f32x2 tu) {
    asm("v_pk_fma_f32 %0, %1, %2, %0 op_sel:[1,1,0] op_sel_hi:[1,0,1] neg_hi:[1,0,0]\n\t"
        "v_pk_fma_f32 %0, %1, %2, %0 op_sel_hi:[0,1,1] neg_lo:[1,0,0] neg_hi:[1,0,0]"
        : "+v"(c) : "v"(s), "v"(tu));
}

// col -= (-s)*tu : lo: c.x += -s.y*tu.y + s.x*tu.x ; hi: c.y += s.y*tu.x + s.x*tu.y
__device__ __forceinline__ void upd_neg(f32x2& c, f32x2 s, f32x2 tu) {
    asm("v_pk_fma_f32 %0, %1, %2, %0 op_sel:[1,1,0] op_sel_hi:[1,0,1] neg_lo:[1,0,0]\n\t"
        "v_pk_fma_f32 %0, %1, %2, %0 op_sel_hi:[0,1,1]"
        : "+v"(c) : "v"(s), "v"(tu));
}

__global__ __launch_bounds__(256, 2)
void negf_all(const float* __restrict__ tri,
              const float* __restrict__ GL,
              const float* __restrict__ GR,
              float* __restrict__ out)
{
    __shared__ float Hcm[400];          // column-major: Hcm[c*20 + r] = H[r][c]
    __shared__ float sgL[H_N], sgR[H_N];
    __shared__ f32x4 stage[12][10];     // per-subgroup pivot-column broadcast

    const int blk   = blockIdx.x;
    const int b     = blk / 9;
    const int chunk = blk - b * 9;
    const int tid   = threadIdx.x;

    // ---- stage H (column-major) + gammas into LDS ----
    const float* triB = tri + b * 210;
    #pragma unroll
    for (int u0 = 0; u0 < 2; ++u0) {
        int u = tid + u0 * 256;
        if (u < 400) {
            int c = u / 20, r = u - c * 20;
            int lo = r < c ? r : c;
            int hi = r < c ? c : r;
            Hcm[u] = triB[triIdx(lo, hi)];
        }
    }
    if (tid < H_N) {
        sgL[tid] = GL[b * H_N + tid];
        sgR[tid] = GR[b * H_N + tid];
    }
    __syncthreads();

    // ---- H output (row-major), exact copy of inputs; one block per b ----
    if (chunk == 0) {
        #pragma unroll
        for (int u0 = 0; u0 < 2; ++u0) {
            int u = tid + u0 * 256;
            if (u < 400) {
                int r = u / 20, c = u - r * 20;
                out[H_OFF + b * 400 + u] = Hcm[c * 20 + r];
            }
        }
    }

    const int lane = tid & 63;
    const int wid  = tid >> 6;
    const int sw   = lane / 20;              // 0..2 active, 3 idle
    const int ll   = lane - sw * 20;         // 0..19 row/col id within subgroup
    const int sg   = wid * 3 + (sw < 3 ? sw : 0);
    const int e    = chunk * 12 + sg;
    if (sw == 3 || e >= NE) return;          // no __syncthreads after this point

    const float gj   = sgR[ll];              // gammaR_j for this lane's column
    const float gamj = 0.5f * (sgL[ll] + gj);
    const float E    = fmaf((float)e, 6.0f / 99.0f, -3.0f);

    // build column ll of A
    f32x2 col[H_N];
    #pragma unroll
    for (int i = 0; i < H_N; ++i) {
        float hv = Hcm[ll * 20 + i];
        col[i].x = (i == ll) ? (E - hv) : (-hv);
        col[i].y = (i == ll) ? gamj : 0.0f;
    }

    f32x2* const myStage = (f32x2*)&stage[sg][0];

    // ---- in-place Gauss-Jordan, fully unrolled (static reg indices) ----
    #pragma unroll
    for (int k = 0; k < H_N; ++k) {
        // every lane publishes its element k: stage[sg][i] = M[k][i]
        myStage[ll] = col[k];                // one ds_write_b64, whole wave
        __builtin_amdgcn_wave_barrier();
        f32x4 q[10];
        #pragma unroll
        for (int qq = 0; qq < 10; ++qq) q[qq] = stage[sg][qq];
        __builtin_amdgcn_wave_barrier();

        // pivot = s_k = M[k][k]; p = 1/pivot (complex reciprocal)
        const float ykx = (k & 1) ? q[k >> 1].z : q[k >> 1].x;
        const float yky = (k & 1) ? q[k >> 1].w : q[k >> 1].y;
        const float den = fmaf(ykx, ykx, yky * yky);
        const float inv = __builtin_amdgcn_rcpf(den);
        const float px  =  ykx * inv;
        const float py  = -yky * inv;

        // t = col[k] * p ; lane k uses tu = [1+px, py] (e_k substitution folded)
        const float tx  = col[k].x * px - col[k].y * py;
        const float ty  = col[k].x * py + col[k].y * px;
        const bool  isk = (ll == k);
        f32x2 tu; tu.x = isk ? (1.0f + px) : tx;  tu.y = isk ? py : ty;
        f32x2 fk; fk.x = isk ? px : tx;           fk.y = isk ? py : ty;

        // col[i] -= y[i]*tu, with y[i] = sigma * s_i, sigma = -1 for i<k
        #pragma unroll
        for (int i = 0; i < H_N; ++i) {
            if (i == k) continue;
            f32x2 s = (i & 1) ? __builtin_shufflevector(q[i >> 1], q[i >> 1], 2, 3)
                              : __builtin_shufflevector(q[i >> 1], q[i >> 1], 0, 1);
            if (i < k) upd_neg(col[i], s, tu);
            else       upd_pos(col[i], s, tu);
        }
        col[k] = fk;
    }

    // ---- epilogue: T partial + diag Im, subgroup reduce, store ----
    float tv = 0.0f, dv = 0.0f;
    #pragma unroll
    for (int i = 0; i < H_N; ++i) {
        float aa = fmaf(col[i].x, col[i].x, col[i].y * col[i].y);
        tv = fmaf(sgL[i], aa, tv);
        dv = (i == ll) ? col[i].y : dv;
    }
    tv *= gj;

    #pragma unroll
    for (int d = 16; d >= 1; d >>= 1) {
        float t2 = __shfl(tv, lane + d, 64);
        float d2 = __shfl(dv, lane + d, 64);
        if (ll + d < 20) { tv += t2; dv += d2; }
    }
    if (ll == 0) {
        out[T_OFF + b * NE + e] = __log10f(fmaxf(tv, 1e-16f));
        out[D_OFF + b * NE + e] = __log10f(fmaxf(-dv, 1e-16f));
    }
}

extern "C" void kernel_launch(void* const* d_in, const int* in_sizes, int n_in,
                              void* d_out, int out_size, void* d_ws, size_t ws_size,
                              hipStream_t stream) {
    const float* tri = (const float*)d_in[0];
    const float* gL  = (const float*)d_in[1];
    const float* gR  = (const float*)d_in[2];
    float* out = (float*)d_out;
    negf_all<<<1024 * 9, 256, 0, stream>>>(tri, gL, gR, out);
}